// Round 2
// baseline (1819.349 us; speedup 1.0000x reference)
//
#include <hip/hip_runtime.h>
#include <hip/hip_bf16.h>
#include <stdint.h>

// Castle attention, bf16 MFMA pipeline.
// Stages: convert -> qkv GEMM (scatter) -> term1/lookahead (masked, bf16)
//   -> scores = Sc - silu(term1 @ lookahead^T)  (block-triangular skip, f32)
//   -> row softmax -> p (bf16, reuses term1 buffer) -> PV -> out GEMM.

typedef unsigned short u16;
typedef __attribute__((ext_vector_type(8))) short s8v;   // 8 x bf16 (as shorts)
typedef __attribute__((ext_vector_type(4))) float f4v;   // MFMA accumulator

#define LDS_STRIDE 40  // 32 k-elements + 8 pad (keeps 16B align, breaks bank aliasing)

__device__ __forceinline__ u16 f2bf(float f) {
  union { float f; unsigned u; } v; v.f = f;
  unsigned r = v.u + 0x7FFFu + ((v.u >> 16) & 1u);
  return (u16)(r >> 16);
}

__device__ __forceinline__ void stage_tile(u16* __restrict__ dst, const u16* __restrict__ src,
                                           int rows, long srcStride, int tid, int nthreads) {
  // copy rows x 32 bf16; each row = 64 B = FOUR 16-B uint4 chunks (8 bf16 each)
  for (int i = tid; i < rows * 4; i += nthreads) {
    int r = i >> 2, seg = i & 3;
    *(uint4*)(&dst[r * LDS_STRIDE + seg * 8]) =
        *(const uint4*)(&src[(long)r * srcStride + seg * 8]);
  }
}

// one 32-wide K-step: 16 MFMAs for a 64x64 per-wave tile
__device__ __forceinline__ void mfma_tile(const u16* As, const u16* Bs, int lane,
                                          int wm, int wn, f4v acc[4][4]) {
  const int rl = lane & 15;
  const int ks = (lane >> 4) * 8;
  s8v a[4], b[4];
#pragma unroll
  for (int m = 0; m < 4; ++m)
    a[m] = *(const s8v*)(&As[(wm * 64 + m * 16 + rl) * LDS_STRIDE + ks]);
#pragma unroll
  for (int n = 0; n < 4; ++n)
    b[n] = *(const s8v*)(&Bs[(wn * 64 + n * 16 + rl) * LDS_STRIDE + ks]);
#pragma unroll
  for (int m = 0; m < 4; ++m)
#pragma unroll
    for (int n = 0; n < 4; ++n)
      acc[m][n] = __builtin_amdgcn_mfma_f32_16x16x32_bf16(a[m], b[n], acc[m][n], 0, 0, 0);
}

__device__ __forceinline__ void zero_acc(f4v acc[4][4]) {
  f4v z = {0.f, 0.f, 0.f, 0.f};
#pragma unroll
  for (int m = 0; m < 4; ++m)
#pragma unroll
    for (int n = 0; n < 4; ++n) acc[m][n] = z;
}

// ---------------- converts ----------------

__global__ void convert_x_kernel(const float* __restrict__ in, u16* __restrict__ out) {
  int i = (blockIdx.x * 256 + threadIdx.x) * 4;
  float4 v = *(const float4*)(&in[i]);
  out[i + 0] = f2bf(v.x);
  out[i + 1] = f2bf(v.y);
  out[i + 2] = f2bf(v.z);
  out[i + 3] = f2bf(v.w);
}

__global__ void transpose_convert_kernel(const float* __restrict__ in, u16* __restrict__ out,
                                         int R, int C) {
  __shared__ float tile[32][33];
  int c0 = blockIdx.x * 32, r0 = blockIdx.y * 32;
  for (int rr = threadIdx.y; rr < 32; rr += 8)
    tile[rr][threadIdx.x] = in[(size_t)(r0 + rr) * C + (c0 + threadIdx.x)];
  __syncthreads();
  for (int cc = threadIdx.y; cc < 32; cc += 8)
    out[(size_t)(c0 + cc) * R + (r0 + threadIdx.x)] = f2bf(tile[threadIdx.x][cc]);
}

// ---------------- qkv projection: [4096,1024] @ [1024,6144] ----------------

__global__ __launch_bounds__(256) void gemm_qkv_kernel(
    const u16* __restrict__ xb, const u16* __restrict__ wqkvT,
    u16* __restrict__ quS, u16* __restrict__ ku, u16* __restrict__ vu,
    u16* __restrict__ qcS, u16* __restrict__ kc, u16* __restrict__ vcT) {
  __shared__ u16 As[128 * LDS_STRIDE], Bs[128 * LDS_STRIDE];
  int bm = blockIdx.x, bn = blockIdx.y;
  int tid = threadIdx.x, lane = tid & 63, w = tid >> 6, wm = w >> 1, wn = w & 1;
  f4v acc[4][4];
  zero_acc(acc);
  for (int kk = 0; kk < 1024; kk += 32) {
    stage_tile(As, xb + (size_t)(bm * 128) * 1024 + kk, 128, 1024, tid, 256);
    stage_tile(Bs, wqkvT + (size_t)(bn * 128) * 1024 + kk, 128, 1024, tid, 256);
    __syncthreads();
    mfma_tile(As, Bs, lane, wm, wn, acc);
    __syncthreads();
  }
#pragma unroll
  for (int m = 0; m < 4; ++m)
#pragma unroll
    for (int n = 0; n < 4; ++n)
#pragma unroll
      for (int j = 0; j < 4; ++j) {
        int row = bm * 128 + wm * 64 + m * 16 + ((lane >> 4) * 4) + j;  // [0,4096)
        int col = bn * 128 + wn * 64 + n * 16 + (lane & 15);            // [0,6144)
        float v = acc[m][n][j];
        int b = row >> 11, nn = row & 2047;
        int s = col >> 10, hh = (col >> 6) & 15, dd = col & 63;
        int bh = (b << 4) + hh;
        size_t idx = ((size_t)bh * 2048 + nn) * 64 + dd;
        switch (s) {
          case 0: quS[idx] = f2bf(v * 0.125f); break;
          case 1: ku[idx] = f2bf(v); break;
          case 2: vu[idx] = f2bf(v); break;
          case 3: qcS[idx] = f2bf(v * 0.125f); break;
          case 4: kc[idx] = f2bf(v); break;
          default: vcT[((size_t)bh * 64 + dd) * 2048 + nn] = f2bf(v); break;
        }
      }
}

// ------------- term1 (z=0, lower tiles) / lookahead (z=1, upper tiles) -------------

__global__ __launch_bounds__(256) void tl_kernel(
    const u16* __restrict__ qcS, const u16* __restrict__ vu,
    const u16* __restrict__ quS, const u16* __restrict__ ku,
    u16* __restrict__ term1, u16* __restrict__ look, int c0) {
  __shared__ u16 As[128 * LDS_STRIDE], Bs[128 * LDS_STRIDE];
  int t = blockIdx.x, lb = blockIdx.y, z = blockIdx.z;
  int bh = c0 + lb;
  int I = 0;
  while ((I + 1) * (I + 2) / 2 <= t) ++I;
  int K = t - I * (I + 1) / 2;
  int rt = z ? K : I;
  int ct = z ? I : K;
  const u16* A = (z ? quS : qcS) + ((size_t)bh * 2048 + rt * 128) * 64;
  const u16* B = (z ? ku : vu) + ((size_t)bh * 2048 + ct * 128) * 64;
  u16* o = (z ? look : term1) + (size_t)lb * 2048 * 2048;
  int tid = threadIdx.x, lane = tid & 63, w = tid >> 6, wm = w >> 1, wn = w & 1;
  f4v acc[4][4];
  zero_acc(acc);
  for (int kk = 0; kk < 64; kk += 32) {
    stage_tile(As, A + kk, 128, 64, tid, 256);
    stage_tile(Bs, B + kk, 128, 64, tid, 256);
    __syncthreads();
    mfma_tile(As, Bs, lane, wm, wn, acc);
    __syncthreads();
  }
  int rbase = rt * 128 + wm * 64, cbase = ct * 128 + wn * 64;
#pragma unroll
  for (int m = 0; m < 4; ++m)
#pragma unroll
    for (int n = 0; n < 4; ++n)
#pragma unroll
      for (int j = 0; j < 4; ++j) {
        int gr = rbase + m * 16 + ((lane >> 4) * 4) + j;
        int gc = cbase + n * 16 + (lane & 15);
        float v = acc[m][n][j];
        if (z)
          v = (gc > gr) ? 1.f / (1.f + __expf(-v)) : 0.f;  // sigmoid, strict upper
        else
          v = (gc > gr) ? 0.f : v;                          // lower incl diag
        o[(size_t)gr * 2048 + gc] = f2bf(v);
      }
}

// ------------- scores = Sc - silu(Su), lower tiles, f32 out -------------

__global__ __launch_bounds__(256) void scores_kernel(
    const u16* __restrict__ term1, const u16* __restrict__ look,
    const u16* __restrict__ qcS, const u16* __restrict__ kc,
    float* __restrict__ sc, int c0) {
  __shared__ u16 As[128 * LDS_STRIDE], Bs[128 * LDS_STRIDE];
  int t = blockIdx.x, lb = blockIdx.y;
  int bh = c0 + lb;
  int I = 0;
  while ((I + 1) * (I + 2) / 2 <= t) ++I;
  int K = t - I * (I + 1) / 2;
  int tid = threadIdx.x, lane = tid & 63, w = tid >> 6, wm = w >> 1, wn = w & 1;
  const u16* Ab = term1 + (size_t)lb * 2048 * 2048 + (size_t)(I * 128) * 2048;
  const u16* Bb = look + (size_t)lb * 2048 * 2048 + (size_t)(K * 128) * 2048;
  f4v acc[4][4];
  zero_acc(acc);
  // Su over j-tiles K..I only (term1 zero above diag, lookahead zero at/below diag)
  for (int jt = K; jt <= I; ++jt) {
    for (int kk = 0; kk < 128; kk += 32) {
      stage_tile(As, Ab + jt * 128 + kk, 128, 2048, tid, 256);
      stage_tile(Bs, Bb + jt * 128 + kk, 128, 2048, tid, 256);
      __syncthreads();
      mfma_tile(As, Bs, lane, wm, wn, acc);
      __syncthreads();
    }
  }
  // acc = -silu(acc)
#pragma unroll
  for (int m = 0; m < 4; ++m)
#pragma unroll
    for (int n = 0; n < 4; ++n)
#pragma unroll
      for (int j = 0; j < 4; ++j) {
        float xv = acc[m][n][j];
        acc[m][n][j] = -(xv / (1.f + __expf(-xv)));
      }
  // += Sc (K=64)
  const u16* Aq = qcS + ((size_t)bh * 2048 + I * 128) * 64;
  const u16* Bk = kc + ((size_t)bh * 2048 + K * 128) * 64;
  for (int kk = 0; kk < 64; kk += 32) {
    stage_tile(As, Aq + kk, 128, 64, tid, 256);
    stage_tile(Bs, Bk + kk, 128, 64, tid, 256);
    __syncthreads();
    mfma_tile(As, Bs, lane, wm, wn, acc);
    __syncthreads();
  }
  float* o = sc + (size_t)lb * 2048 * 2048;
#pragma unroll
  for (int m = 0; m < 4; ++m)
#pragma unroll
    for (int n = 0; n < 4; ++n)
#pragma unroll
      for (int j = 0; j < 4; ++j) {
        int gr = I * 128 + wm * 64 + m * 16 + ((lane >> 4) * 4) + j;
        int gc = K * 128 + wn * 64 + n * 16 + (lane & 15);
        o[(size_t)gr * 2048 + gc] = acc[m][n][j];
      }
}

// ------------- row softmax (k <= i), p in bf16 (reuses term1 buffer) -------------

__global__ __launch_bounds__(256) void softmax_kernel(const float* __restrict__ sc,
                                                      u16* __restrict__ p) {
  int i = blockIdx.x, lb = blockIdx.y;
  const float* srow = sc + ((size_t)lb * 2048 + i) * 2048;
  u16* prow = p + ((size_t)lb * 2048 + i) * 2048;
  int tid = threadIdx.x, lane = tid & 63, w = tid >> 6;
  int len = i + 1;
  __shared__ float red[4];
  float m = -3.4e38f;
  for (int k = tid; k < len; k += 256) m = fmaxf(m, srow[k]);
  for (int o = 32; o > 0; o >>= 1) m = fmaxf(m, __shfl_xor(m, o, 64));
  if (lane == 0) red[w] = m;
  __syncthreads();
  m = fmaxf(fmaxf(red[0], red[1]), fmaxf(red[2], red[3]));
  __syncthreads();
  float s = 0.f;
  for (int k = tid; k < len; k += 256) s += __expf(srow[k] - m);
  for (int o = 32; o > 0; o >>= 1) s += __shfl_xor(s, o, 64);
  if (lane == 0) red[w] = s;
  __syncthreads();
  s = red[0] + red[1] + red[2] + red[3];
  float inv = 1.f / s;
  for (int k = tid; k < len; k += 256) prow[k] = f2bf(__expf(srow[k] - m) * inv);
  int zend = ((i >> 7) + 1) << 7;  // zero to end of the diagonal 128-tile
  for (int k = len + tid; k < zend; k += 256) prow[k] = 0;
}

// ------------- PV: O = p @ vc  (k-tiles <= I), writes attn_out [b,n,h*d] -------------

__global__ __launch_bounds__(128) void pv_kernel(const u16* __restrict__ p,
                                                 const u16* __restrict__ vcT,
                                                 u16* __restrict__ attn, int c0) {
  __shared__ u16 As[128 * LDS_STRIDE], Bs[64 * LDS_STRIDE];
  int I = blockIdx.x, lb = blockIdx.y, bh = c0 + lb;
  int tid = threadIdx.x, lane = tid & 63, w = tid >> 6;  // 2 waves, 64 rows each
  const u16* Ab = p + (size_t)lb * 2048 * 2048 + (size_t)(I * 128) * 2048;
  const u16* Bb = vcT + (size_t)bh * 64 * 2048;
  f4v acc[4][4];
  zero_acc(acc);
  for (int kt = 0; kt <= I; ++kt) {
    for (int kk = 0; kk < 128; kk += 32) {
      stage_tile(As, Ab + kt * 128 + kk, 128, 2048, tid, 128);
      stage_tile(Bs, Bb + kt * 128 + kk, 64, 2048, tid, 128);
      __syncthreads();
      mfma_tile(As, Bs, lane, w, 0, acc);
      __syncthreads();
    }
  }
  int b = bh >> 4, hh = bh & 15;
  int rbase = I * 128 + w * 64;
#pragma unroll
  for (int m = 0; m < 4; ++m)
#pragma unroll
    for (int n = 0; n < 4; ++n)
#pragma unroll
      for (int j = 0; j < 4; ++j) {
        int gr = rbase + m * 16 + ((lane >> 4) * 4) + j;  // seq position
        int dd = n * 16 + (lane & 15);                    // head dim
        attn[((size_t)b * 2048 + gr) * 1024 + hh * 64 + dd] = f2bf(acc[m][n][j]);
      }
}

// ------------- final: out = attn_out @ W_out, f32 -------------

__global__ __launch_bounds__(256) void gemm_out_kernel(const u16* __restrict__ attn,
                                                       const u16* __restrict__ woutT,
                                                       float* __restrict__ out) {
  __shared__ u16 As[128 * LDS_STRIDE], Bs[128 * LDS_STRIDE];
  int bm = blockIdx.x, bn = blockIdx.y;
  int tid = threadIdx.x, lane = tid & 63, w = tid >> 6, wm = w >> 1, wn = w & 1;
  f4v acc[4][4];
  zero_acc(acc);
  for (int kk = 0; kk < 1024; kk += 32) {
    stage_tile(As, attn + (size_t)(bm * 128) * 1024 + kk, 128, 1024, tid, 256);
    stage_tile(Bs, woutT + (size_t)(bn * 128) * 1024 + kk, 128, 1024, tid, 256);
    __syncthreads();
    mfma_tile(As, Bs, lane, wm, wn, acc);
    __syncthreads();
  }
#pragma unroll
  for (int m = 0; m < 4; ++m)
#pragma unroll
    for (int n = 0; n < 4; ++n)
#pragma unroll
      for (int j = 0; j < 4; ++j) {
        int row = bm * 128 + wm * 64 + m * 16 + ((lane >> 4) * 4) + j;
        int col = bn * 128 + wn * 64 + n * 16 + (lane & 15);
        out[(size_t)row * 1024 + col] = acc[m][n][j];
      }
}

// ---------------- host ----------------

extern "C" void kernel_launch(void* const* d_in, const int* in_sizes, int n_in,
                              void* d_out, int out_size, void* d_ws, size_t ws_size,
                              hipStream_t stream) {
  const float* x = (const float*)d_in[0];
  const float* Wqkv = (const float*)d_in[1];
  const float* Wout = (const float*)d_in[2];
  float* out = (float*)d_out;

  char* base = (char*)d_ws;
  size_t off = 0;
  auto alloc = [&](size_t bytes) -> void* {
    void* p = base + off;
    off += (bytes + 255) & ~(size_t)255;
    return p;
  };

  u16* xb = (u16*)alloc(4096ull * 1024 * 2);
  u16* wqkvT = (u16*)alloc(6144ull * 1024 * 2);
  u16* woutT = (u16*)alloc(1024ull * 1024 * 2);
  u16* quS = (u16*)alloc(32ull * 2048 * 64 * 2);
  u16* ku = (u16*)alloc(32ull * 2048 * 64 * 2);
  u16* vu = (u16*)alloc(32ull * 2048 * 64 * 2);
  u16* qcS = (u16*)alloc(32ull * 2048 * 64 * 2);
  u16* kc = (u16*)alloc(32ull * 2048 * 64 * 2);
  u16* vcT = (u16*)alloc(32ull * 2048 * 64 * 2);
  u16* attn = (u16*)alloc(4096ull * 1024 * 2);

  // per-(b,h) scratch: term1(bf16) + lookahead(bf16) + scores(f32)
  size_t perBH = 2048ull * 2048 * (2 + 2 + 4);
  size_t remain = (ws_size > off) ? (ws_size - off) : 0;
  int chunk = (int)(remain / perBH);
  if (chunk < 1) chunk = 1;
  if (chunk > 32) chunk = 32;
  u16* term1 = (u16*)alloc((size_t)chunk * 2048 * 2048 * 2);
  u16* look = (u16*)alloc((size_t)chunk * 2048 * 2048 * 2);
  float* sc = (float*)alloc((size_t)chunk * 2048 * 2048 * 4);

  convert_x_kernel<<<4096, 256, 0, stream>>>(x, xb);
  transpose_convert_kernel<<<dim3(192, 32), dim3(32, 8), 0, stream>>>(Wqkv, wqkvT, 1024, 6144);
  transpose_convert_kernel<<<dim3(32, 32), dim3(32, 8), 0, stream>>>(Wout, woutT, 1024, 1024);
  gemm_qkv_kernel<<<dim3(32, 48), 256, 0, stream>>>(xb, wqkvT, quS, ku, vu, qcS, kc, vcT);

  for (int c0 = 0; c0 < 32; c0 += chunk) {
    int nb = (32 - c0 < chunk) ? (32 - c0) : chunk;
    tl_kernel<<<dim3(136, nb, 2), 256, 0, stream>>>(qcS, vu, quS, ku, term1, look, c0);
    scores_kernel<<<dim3(136, nb), 256, 0, stream>>>(term1, look, qcS, kc, sc, c0);
    softmax_kernel<<<dim3(2048, nb), 256, 0, stream>>>(sc, term1);  // p overwrites term1
    pv_kernel<<<dim3(16, nb), 128, 0, stream>>>(term1, vcT, attn, c0);
  }
  gemm_out_kernel<<<dim3(32, 8), 256, 0, stream>>>(attn, woutT, out);
}

// Round 3
// 560.739 us; speedup vs baseline: 3.2446x; 3.2446x over previous
//
#include <hip/hip_runtime.h>
#include <hip/hip_bf16.h>
#include <stdint.h>

// Castle attention, bf16 MFMA pipeline, split-flash version.
// convert -> qkv GEMM (scatter) -> tl (packed swizzled triangular tiles)
//   -> castle (per score-tile: Su, -silu, +Sc, mask, local softmax, PV -> partial O)
//   -> combine (flash-merge partials) -> out GEMM.

typedef unsigned short u16;
typedef __attribute__((ext_vector_type(8))) short s8v;   // 8 x bf16
typedef __attribute__((ext_vector_type(4))) float f4v;   // MFMA accumulator

#define LDS_STRIDE 40

__device__ __forceinline__ u16 f2bf(float f) {
  union { float f; unsigned u; } v; v.f = f;
  unsigned r = v.u + 0x7FFFu + ((v.u >> 16) & 1u);
  return (u16)(r >> 16);
}
__device__ __forceinline__ float bf2f(u16 u) {
  union { unsigned u; float f; } v; v.u = ((unsigned)u) << 16; return v.f;
}

// swizzled element index within a 128-col (or 64-col) bf16 tile:
// byte ^= ((row&7)<<4)  ->  elem ^= ((row&7)<<3)
__device__ __forceinline__ int swz128(int r, int c) { return r * 128 + (c ^ ((r & 7) << 3)); }
__device__ __forceinline__ int swz64v(int r, int c) { return r * 64 + (c ^ ((r & 7) << 3)); }

typedef __attribute__((address_space(1))) const void* gas_t;
typedef __attribute__((address_space(3))) void* las_t;
__device__ __forceinline__ void gld16(const void* g, void* l) {
  __builtin_amdgcn_global_load_lds((gas_t)g, (las_t)l, 16, 0, 0);
}

__device__ __forceinline__ void stage_tile(u16* __restrict__ dst, const u16* __restrict__ src,
                                           int rows, long srcStride, int tid, int nthreads) {
  for (int i = tid; i < rows * 4; i += nthreads) {
    int r = i >> 2, seg = i & 3;
    *(uint4*)(&dst[r * LDS_STRIDE + seg * 8]) =
        *(const uint4*)(&src[(long)r * srcStride + seg * 8]);
  }
}

__device__ __forceinline__ void mfma_tile(const u16* As, const u16* Bs, int lane,
                                          int wm, int wn, f4v acc[4][4]) {
  const int rl = lane & 15;
  const int ks = (lane >> 4) * 8;
  s8v a[4], b[4];
#pragma unroll
  for (int m = 0; m < 4; ++m)
    a[m] = *(const s8v*)(&As[(wm * 64 + m * 16 + rl) * LDS_STRIDE + ks]);
#pragma unroll
  for (int n = 0; n < 4; ++n)
    b[n] = *(const s8v*)(&Bs[(wn * 64 + n * 16 + rl) * LDS_STRIDE + ks]);
#pragma unroll
  for (int m = 0; m < 4; ++m)
#pragma unroll
    for (int n = 0; n < 4; ++n)
      acc[m][n] = __builtin_amdgcn_mfma_f32_16x16x32_bf16(a[m], b[n], acc[m][n], 0, 0, 0);
}

__device__ __forceinline__ void zero_acc(f4v acc[4][4]) {
  f4v z = {0.f, 0.f, 0.f, 0.f};
#pragma unroll
  for (int m = 0; m < 4; ++m)
#pragma unroll
    for (int n = 0; n < 4; ++n) acc[m][n] = z;
}

// ---------------- converts ----------------

__global__ void convert_x_kernel(const float* __restrict__ in, u16* __restrict__ out) {
  int i = (blockIdx.x * 256 + threadIdx.x) * 4;
  float4 v = *(const float4*)(&in[i]);
  out[i + 0] = f2bf(v.x);
  out[i + 1] = f2bf(v.y);
  out[i + 2] = f2bf(v.z);
  out[i + 3] = f2bf(v.w);
}

__global__ void transpose_convert_kernel(const float* __restrict__ in, u16* __restrict__ out,
                                         int R, int C) {
  __shared__ float tile[32][33];
  int c0 = blockIdx.x * 32, r0 = blockIdx.y * 32;
  for (int rr = threadIdx.y; rr < 32; rr += 8)
    tile[rr][threadIdx.x] = in[(size_t)(r0 + rr) * C + (c0 + threadIdx.x)];
  __syncthreads();
  for (int cc = threadIdx.y; cc < 32; cc += 8)
    out[(size_t)(c0 + cc) * R + (r0 + threadIdx.x)] = f2bf(tile[threadIdx.x][cc]);
}

// ---------------- qkv projection ----------------

__global__ __launch_bounds__(256) void gemm_qkv_kernel(
    const u16* __restrict__ xb, const u16* __restrict__ wqkvT,
    u16* __restrict__ quS, u16* __restrict__ ku, u16* __restrict__ vu,
    u16* __restrict__ qcS, u16* __restrict__ kc, u16* __restrict__ vcT) {
  __shared__ u16 As[128 * LDS_STRIDE], Bs[128 * LDS_STRIDE];
  int bm = blockIdx.x, bn = blockIdx.y;
  int tid = threadIdx.x, lane = tid & 63, w = tid >> 6, wm = w >> 1, wn = w & 1;
  f4v acc[4][4];
  zero_acc(acc);
  for (int kk = 0; kk < 1024; kk += 32) {
    stage_tile(As, xb + (size_t)(bm * 128) * 1024 + kk, 128, 1024, tid, 256);
    stage_tile(Bs, wqkvT + (size_t)(bn * 128) * 1024 + kk, 128, 1024, tid, 256);
    __syncthreads();
    mfma_tile(As, Bs, lane, wm, wn, acc);
    __syncthreads();
  }
#pragma unroll
  for (int m = 0; m < 4; ++m)
#pragma unroll
    for (int n = 0; n < 4; ++n)
#pragma unroll
      for (int j = 0; j < 4; ++j) {
        int row = bm * 128 + wm * 64 + m * 16 + ((lane >> 4) * 4) + j;
        int col = bn * 128 + wn * 64 + n * 16 + (lane & 15);
        float v = acc[m][n][j];
        int b = row >> 11, nn = row & 2047;
        int s = col >> 10, hh = (col >> 6) & 15, dd = col & 63;
        int bh = (b << 4) + hh;
        size_t idx = ((size_t)bh * 2048 + nn) * 64 + dd;
        switch (s) {
          case 0: quS[idx] = f2bf(v * 0.125f); break;
          case 1: ku[idx] = f2bf(v); break;
          case 2: vu[idx] = f2bf(v); break;
          case 3: qcS[idx] = f2bf(v * 0.125f); break;
          case 4: kc[idx] = f2bf(v); break;
          default: vcT[((size_t)bh * 64 + dd) * 2048 + nn] = f2bf(v); break;
        }
      }
}

// ------------- term1 / lookahead -> packed swizzled tiles -------------
// term1 tile (I,j) and look tile (K,j) both live at packed index c(c+1)/2+r
// (r=row-tile, c=col-tile, r<=c ... term1: r=I>=c=j uses I(I+1)/2+j; see castle)

__global__ __launch_bounds__(256) void tl_kernel(
    const u16* __restrict__ qcS, const u16* __restrict__ vu,
    const u16* __restrict__ quS, const u16* __restrict__ ku,
    u16* __restrict__ term1p, u16* __restrict__ lookp, int c0) {
  __shared__ u16 As[128 * LDS_STRIDE], Bs[128 * LDS_STRIDE];
  int t = blockIdx.x, lb = blockIdx.y, z = blockIdx.z;
  int bh = c0 + lb;
  int I = 0;
  while ((I + 1) * (I + 2) / 2 <= t) ++I;
  int K = t - I * (I + 1) / 2;
  int rt = z ? K : I;
  int ct = z ? I : K;
  const u16* A = (z ? quS : qcS) + ((size_t)bh * 2048 + rt * 128) * 64;
  const u16* B = (z ? ku : vu) + ((size_t)bh * 2048 + ct * 128) * 64;
  u16* o = (z ? lookp : term1p) + ((size_t)lb * 136 + t) * 16384;
  int tid = threadIdx.x, lane = tid & 63, w = tid >> 6, wm = w >> 1, wn = w & 1;
  f4v acc[4][4];
  zero_acc(acc);
  for (int kk = 0; kk < 64; kk += 32) {
    stage_tile(As, A + kk, 128, 64, tid, 256);
    stage_tile(Bs, B + kk, 128, 64, tid, 256);
    __syncthreads();
    mfma_tile(As, Bs, lane, wm, wn, acc);
    __syncthreads();
  }
#pragma unroll
  for (int m = 0; m < 4; ++m)
#pragma unroll
    for (int n = 0; n < 4; ++n)
#pragma unroll
      for (int j = 0; j < 4; ++j) {
        int lr = wm * 64 + m * 16 + ((lane >> 4) * 4) + j;
        int lc = wn * 64 + n * 16 + (lane & 15);
        int gr = rt * 128 + lr, gc = ct * 128 + lc;
        float v = acc[m][n][j];
        if (z)
          v = (gc > gr) ? 1.f / (1.f + __expf(-v)) : 0.f;  // sigmoid, strict upper
        else
          v = (gc > gr) ? 0.f : v;                          // lower incl diag
        o[swz128(lr, lc)] = f2bf(v);
      }
}

// ------------- castle: per (I,K) tile, Su -> -silu -> +Sc -> mask -> softmax -> PV -------------

__global__ __launch_bounds__(256, 2) void castle_kernel(
    const u16* __restrict__ term1p, const u16* __restrict__ lookp,
    const u16* __restrict__ qcS, const u16* __restrict__ kc,
    const u16* __restrict__ vcT,
    u16* __restrict__ opart, float* __restrict__ ml, int c0) {
  __shared__ u16 sA[16384];  // term1 j-tile (swizzled) / P tile
  __shared__ u16 sB[16384];  // look j-tile / [Ks | Vs]
  int sid = blockIdx.x, lb = blockIdx.y, bh = c0 + lb;
  // decode diagonal-major (largest diagonal first): d = I-K from 15 down to 0
  int d = 15, acc0 = 0;
  while (acc0 + (16 - d) <= sid) { acc0 += 16 - d; --d; }
  int K = sid - acc0;
  int I = d + K;
  int t = I * (I + 1) / 2 + K;

  int tid = threadIdx.x, lane = tid & 63, w = tid >> 6;
  int g = lane >> 4, l15 = lane & 15;

  const u16* t1b = term1p + (size_t)lb * 136 * 16384;
  const u16* lkb = lookp + (size_t)lb * 136 * 16384;

  // qc fragments in registers (reused for Sc)
  s8v qa[2][2];
#pragma unroll
  for (int mg = 0; mg < 2; ++mg)
#pragma unroll
    for (int kk = 0; kk < 2; ++kk)
      qa[mg][kk] = *(const s8v*)(&qcS[((size_t)bh * 2048 + I * 128 + w * 32 + mg * 16 + l15) * 64 +
                                      kk * 32 + g * 8]);

  f4v su[2][8];
  {
    f4v z = {0.f, 0.f, 0.f, 0.f};
#pragma unroll
    for (int mg = 0; mg < 2; ++mg)
#pragma unroll
      for (int n = 0; n < 8; ++n) su[mg][n] = z;
  }

  int bo = w * 1024 + (lane << 4);  // per-thread byte slot for staging

  // ---- Su over j in [K..I] ----
  for (int j = K; j <= I; ++j) {
    __syncthreads();  // everyone done reading sA/sB
    const char* srcA = (const char*)(t1b + (size_t)(I * (I + 1) / 2 + j) * 16384);
    const char* srcB = (const char*)(lkb + (size_t)(j * (j + 1) / 2 + K) * 16384);
#pragma unroll
    for (int it = 0; it < 8; ++it) {
      gld16(srcA + bo + it * 4096, (char*)sA + bo + it * 4096);
      gld16(srcB + bo + it * 4096, (char*)sB + bo + it * 4096);
    }
    __syncthreads();  // drains vmcnt -> tiles ready
#pragma unroll
    for (int kk = 0; kk < 4; ++kk) {
      s8v a[2], b[8];
      int c = kk * 32 + g * 8;
#pragma unroll
      for (int mg = 0; mg < 2; ++mg)
        a[mg] = *(const s8v*)(&sA[swz128(w * 32 + mg * 16 + l15, c)]);
#pragma unroll
      for (int n = 0; n < 8; ++n)
        b[n] = *(const s8v*)(&sB[swz128(n * 16 + l15, c)]);
#pragma unroll
      for (int mg = 0; mg < 2; ++mg)
#pragma unroll
        for (int n = 0; n < 8; ++n)
          su[mg][n] = __builtin_amdgcn_mfma_f32_16x16x32_bf16(a[mg], b[n], su[mg][n], 0, 0, 0);
    }
  }

  // ---- stage Ks (kc tile) and Vs (vc slice) into sB, overlap with silu ----
  __syncthreads();  // done reading sB (look)
  {
    // Ks: 128 rows x 64 d, swizzled, 16 KB at sB[0..8192)
#pragma unroll
    for (int it = 0; it < 4; ++it) {
      int o = bo + it * 4096;
      int row = o >> 7, lo = o & 127;
      const u16* src = kc + ((size_t)bh * 2048 + K * 128 + row) * 64 +
                       ((lo ^ ((row & 7) << 4)) >> 1);
      gld16(src, (char*)sB + o);
    }
    // Vs: 64 rows (d) x 128 k, swizzled, 16 KB at sB[8192..16384)
#pragma unroll
    for (int it = 0; it < 4; ++it) {
      int o = bo + it * 4096;
      int rowd = o >> 8, lo = o & 255;
      const u16* src = vcT + ((size_t)bh * 64 + rowd) * 2048 + K * 128 +
                       ((lo ^ ((rowd & 7) << 4)) >> 1);
      gld16(src, (char*)sB + 16384 + o);
    }
  }
  // silu on Su while loads fly: su = -silu(su)
#pragma unroll
  for (int mg = 0; mg < 2; ++mg)
#pragma unroll
    for (int n = 0; n < 8; ++n)
#pragma unroll
      for (int j4 = 0; j4 < 4; ++j4) {
        float xv = su[mg][n][j4];
        su[mg][n][j4] = -(xv / (1.f + __expf(-xv)));
      }
  __syncthreads();  // Ks/Vs ready

  // ---- Sc accumulate ----
#pragma unroll
  for (int kk = 0; kk < 2; ++kk) {
    s8v b[8];
    int c = kk * 32 + g * 8;
#pragma unroll
    for (int n = 0; n < 8; ++n)
      b[n] = *(const s8v*)(&sB[swz64v(n * 16 + l15, c)]);
#pragma unroll
    for (int mg = 0; mg < 2; ++mg)
#pragma unroll
      for (int n = 0; n < 8; ++n)
        su[mg][n] = __builtin_amdgcn_mfma_f32_16x16x32_bf16(qa[mg][kk], b[n], su[mg][n], 0, 0, 0);
  }

  // ---- causal mask (diagonal tile only) ----
  if (K == I) {
#pragma unroll
    for (int mg = 0; mg < 2; ++mg)
#pragma unroll
      for (int n = 0; n < 8; ++n)
#pragma unroll
        for (int j4 = 0; j4 < 4; ++j4) {
          int lr = w * 32 + mg * 16 + g * 4 + j4;
          int lc = n * 16 + l15;
          if (lc > lr) su[mg][n][j4] = -3.0e38f;
        }
  }

  // ---- local softmax: row max, exp, row sum; P -> sA (swizzled) ----
  float mrow[2][4], lrow[2][4];
#pragma unroll
  for (int mg = 0; mg < 2; ++mg)
#pragma unroll
    for (int j4 = 0; j4 < 4; ++j4) {
      float v = -3.0e38f;
#pragma unroll
      for (int n = 0; n < 8; ++n) v = fmaxf(v, su[mg][n][j4]);
      v = fmaxf(v, __shfl_xor(v, 1));
      v = fmaxf(v, __shfl_xor(v, 2));
      v = fmaxf(v, __shfl_xor(v, 4));
      v = fmaxf(v, __shfl_xor(v, 8));
      mrow[mg][j4] = v;
    }
  __syncthreads();  // sA (term1) no longer read by anyone -> safe to write P
#pragma unroll
  for (int mg = 0; mg < 2; ++mg)
#pragma unroll
    for (int j4 = 0; j4 < 4; ++j4) {
      float sum = 0.f;
      int prow = w * 32 + mg * 16 + g * 4 + j4;
#pragma unroll
      for (int n = 0; n < 8; ++n) {
        float e = __expf(su[mg][n][j4] - mrow[mg][j4]);
        sum += e;
        sA[swz128(prow, n * 16 + l15)] = f2bf(e);
      }
      sum += __shfl_xor(sum, 1);
      sum += __shfl_xor(sum, 2);
      sum += __shfl_xor(sum, 4);
      sum += __shfl_xor(sum, 8);
      lrow[mg][j4] = sum;
    }
  __syncthreads();  // P visible

  // ---- PV: O = P @ Vs ----
  f4v o[2][4];
  {
    f4v z = {0.f, 0.f, 0.f, 0.f};
#pragma unroll
    for (int mg = 0; mg < 2; ++mg)
#pragma unroll
      for (int nd = 0; nd < 4; ++nd) o[mg][nd] = z;
  }
#pragma unroll
  for (int kk = 0; kk < 4; ++kk) {
    s8v pa[2], vb[4];
    int c = kk * 32 + g * 8;
#pragma unroll
    for (int mg = 0; mg < 2; ++mg)
      pa[mg] = *(const s8v*)(&sA[swz128(w * 32 + mg * 16 + l15, c)]);
#pragma unroll
    for (int nd = 0; nd < 4; ++nd)
      vb[nd] = *(const s8v*)(&sB[8192 + swz128(nd * 16 + l15, c)]);
#pragma unroll
    for (int mg = 0; mg < 2; ++mg)
#pragma unroll
      for (int nd = 0; nd < 4; ++nd)
        o[mg][nd] = __builtin_amdgcn_mfma_f32_16x16x32_bf16(pa[mg], vb[nd], o[mg][nd], 0, 0, 0);
  }

  // ---- write partials ----
  size_t tb = (size_t)lb * 136 + t;
#pragma unroll
  for (int mg = 0; mg < 2; ++mg)
#pragma unroll
    for (int nd = 0; nd < 4; ++nd)
#pragma unroll
      for (int j4 = 0; j4 < 4; ++j4) {
        int prow = w * 32 + mg * 16 + g * 4 + j4;
        int dcol = nd * 16 + l15;
        opart[(tb * 128 + prow) * 64 + dcol] = f2bf(o[mg][nd][j4]);
      }
  if (l15 == 0) {
#pragma unroll
    for (int mg = 0; mg < 2; ++mg)
#pragma unroll
      for (int j4 = 0; j4 < 4; ++j4) {
        int prow = w * 32 + mg * 16 + g * 4 + j4;
        ml[tb * 256 + prow] = mrow[mg][j4];
        ml[tb * 256 + 128 + prow] = lrow[mg][j4];
      }
  }
}

// ------------- combine: flash-merge the <=16 partials per (I, head) -------------

__global__ __launch_bounds__(256) void combine_kernel(const u16* __restrict__ opart,
                                                      const float* __restrict__ ml,
                                                      u16* __restrict__ attn, int c0) {
  int lb = blockIdx.x, I = blockIdx.y, bh = c0 + lb;
  int tid = threadIdx.x;
  int row = tid >> 1, dh = (tid & 1) << 5;
  float M = -3.0e38f, L = 0.f;
  float O[32];
#pragma unroll
  for (int i = 0; i < 32; ++i) O[i] = 0.f;
  for (int K = 0; K <= I; ++K) {
    size_t tb = (size_t)lb * 136 + I * (I + 1) / 2 + K;
    float m = ml[tb * 256 + row];
    float l = ml[tb * 256 + 128 + row];
    float newM = fmaxf(M, m);
    float so = __expf(M - newM), sn = __expf(m - newM);
    L = L * so + l * sn;
    const u16* op = opart + (tb * 128 + row) * 64 + dh;
#pragma unroll
    for (int q = 0; q < 4; ++q) {
      s8v ov = *(const s8v*)(op + q * 8);
#pragma unroll
      for (int e = 0; e < 8; ++e)
        O[q * 8 + e] = O[q * 8 + e] * so + bf2f((u16)ov[e]) * sn;
    }
    M = newM;
  }
  float inv = 1.f / L;
  int b = bh >> 4, hh = bh & 15;
  u16* dst = attn + ((size_t)b * 2048 + I * 128 + row) * 1024 + hh * 64 + dh;
#pragma unroll
  for (int i = 0; i < 32; ++i) dst[i] = f2bf(O[i] * inv);
}

// ------------- final: out = attn_out @ W_out, f32 -------------

__global__ __launch_bounds__(256) void gemm_out_kernel(const u16* __restrict__ attn,
                                                       const u16* __restrict__ woutT,
                                                       float* __restrict__ out) {
  __shared__ u16 As[128 * LDS_STRIDE], Bs[128 * LDS_STRIDE];
  int bm = blockIdx.x, bn = blockIdx.y;
  int tid = threadIdx.x, lane = tid & 63, w = tid >> 6, wm = w >> 1, wn = w & 1;
  f4v acc[4][4];
  zero_acc(acc);
  for (int kk = 0; kk < 1024; kk += 32) {
    stage_tile(As, attn + (size_t)(bm * 128) * 1024 + kk, 128, 1024, tid, 256);
    stage_tile(Bs, woutT + (size_t)(bn * 128) * 1024 + kk, 128, 1024, tid, 256);
    __syncthreads();
    mfma_tile(As, Bs, lane, wm, wn, acc);
    __syncthreads();
  }
#pragma unroll
  for (int m = 0; m < 4; ++m)
#pragma unroll
    for (int n = 0; n < 4; ++n)
#pragma unroll
      for (int j = 0; j < 4; ++j) {
        int row = bm * 128 + wm * 64 + m * 16 + ((lane >> 4) * 4) + j;
        int col = bn * 128 + wn * 64 + n * 16 + (lane & 15);
        out[(size_t)row * 1024 + col] = acc[m][n][j];
      }
}

// ---------------- host ----------------

extern "C" void kernel_launch(void* const* d_in, const int* in_sizes, int n_in,
                              void* d_out, int out_size, void* d_ws, size_t ws_size,
                              hipStream_t stream) {
  const float* x = (const float*)d_in[0];
  const float* Wqkv = (const float*)d_in[1];
  const float* Wout = (const float*)d_in[2];
  float* out = (float*)d_out;

  char* base = (char*)d_ws;
  size_t off = 0;
  auto alloc = [&](size_t bytes) -> void* {
    void* p = base + off;
    off += (bytes + 255) & ~(size_t)255;
    return p;
  };

  // fixed-live buffers
  u16* woutT = (u16*)alloc(1024ull * 1024 * 2);
  u16* quS = (u16*)alloc(32ull * 2048 * 64 * 2);
  u16* ku = (u16*)alloc(32ull * 2048 * 64 * 2);
  u16* vu = (u16*)alloc(32ull * 2048 * 64 * 2);
  u16* qcS = (u16*)alloc(32ull * 2048 * 64 * 2);
  u16* kc = (u16*)alloc(32ull * 2048 * 64 * 2);
  u16* vcT = (u16*)alloc(32ull * 2048 * 64 * 2);
  u16* attn = (u16*)alloc(4096ull * 1024 * 2);

  // per-head chunk scratch: packed term1 + packed look + opart(bf16) + ml(f32)
  size_t perBH = 136ull * 16384 * 2 * 2 + 136ull * 128 * 64 * 2 + 136ull * 256 * 4;
  size_t remain = (ws_size > off) ? (ws_size - off) : 0;
  int chunk = (int)(remain / perBH);
  if (chunk < 1) chunk = 1;
  if (chunk > 32) chunk = 32;
  u16* term1p = (u16*)alloc((size_t)chunk * 136 * 16384 * 2);
  u16* lookp = (u16*)alloc((size_t)chunk * 136 * 16384 * 2);
  u16* opart = (u16*)alloc((size_t)chunk * 136 * 8192 * 2);
  float* mlb = (float*)alloc((size_t)chunk * 136 * 256 * 4);

  // xb / wqkvT are dead after gemm_qkv -> overlay them on the chunk region
  u16* xb = term1p;                       // 8 MB
  u16* wqkvT = term1p + 4096ull * 1024;   // 12 MB

  convert_x_kernel<<<4096, 256, 0, stream>>>(x, xb);
  transpose_convert_kernel<<<dim3(192, 32), dim3(32, 8), 0, stream>>>(Wqkv, wqkvT, 1024, 6144);
  transpose_convert_kernel<<<dim3(32, 32), dim3(32, 8), 0, stream>>>(Wout, woutT, 1024, 1024);
  gemm_qkv_kernel<<<dim3(32, 48), 256, 0, stream>>>(xb, wqkvT, quS, ku, vu, qcS, kc, vcT);

  for (int c0 = 0; c0 < 32; c0 += chunk) {
    int nb = (32 - c0 < chunk) ? (32 - c0) : chunk;
    tl_kernel<<<dim3(136, nb, 2), 256, 0, stream>>>(qcS, vu, quS, ku, term1p, lookp, c0);
    castle_kernel<<<dim3(136, nb), 256, 0, stream>>>(term1p, lookp, qcS, kc, vcT, opart, mlb, c0);
    combine_kernel<<<dim3(nb, 16), 256, 0, stream>>>(opart, mlb, attn, c0);
  }
  gemm_out_kernel<<<dim3(32, 8), 256, 0, stream>>>(attn, woutT, out);
}